// Round 1
// baseline (601.972 us; speedup 1.0000x reference)
//
#include <hip/hip_runtime.h>

#define B_TOTAL 131072
#define KDIM    512
#define NDIM    100
#define MT      128      // batches per block (GEMM)
#define KC      32       // K chunk
#define NPAD    112      // padded N for LDS / per-thread 28-col slices
#define NTERMS  10       // Taylor degree for expm

// ---------------------------------------------------------------------------
// Kernel 1: lie_alg[b, :] = z[b, :] @ basis  (fp32, VALU)
// M=131072, K=512, N=100. Block: 256 thr = 64 m-threads x 4 n-threads.
// Micro-tile 2 rows x 28 cols. basis chunk staged in LDS (zero-padded to 112),
// z chunk held in registers (L1 dedups the 4-way lane duplication).
// Writes lie_alg into `out` (reused as scratch; expm kernel rewrites in place).
// ---------------------------------------------------------------------------
__global__ __launch_bounds__(256) void lie_gemm_kernel(
    const float* __restrict__ z, const float* __restrict__ basis,
    float* __restrict__ out)
{
    __shared__ float bt[KC][NPAD];   // 32*112*4 = 14336 B

    const int t   = threadIdx.x;
    const int mt  = t >> 2;          // 0..63
    const int nt  = t & 3;           // 0..3
    const int row0 = blockIdx.x * MT + 2 * mt;
    const int n0   = nt * 28;        // 28*4 = 112 cols covered (>=100)

    float acc0[28], acc1[28];
#pragma unroll
    for (int c = 0; c < 28; ++c) { acc0[c] = 0.f; acc1[c] = 0.f; }

    for (int kc = 0; kc < KDIM; kc += KC) {
        __syncthreads();
        // stage basis chunk [KC][NDIM] -> LDS, zero-pad cols 100..111
        // KC*NPAD = 3584 = 14 * 256 -> uniform loop, no tail
        for (int f = t; f < KC * NPAD; f += 256) {
            const int r = f / NPAD;
            const int c = f - r * NPAD;
            bt[r][c] = (c < NDIM) ? basis[(kc + r) * NDIM + c] : 0.f;
        }
        __syncthreads();

        // z chunk -> registers (2 rows x KC), vectorized 16B loads
        float zr0[KC], zr1[KC];
#pragma unroll
        for (int s = 0; s < KC / 4; ++s) {
            *(float4*)&zr0[s * 4] =
                *(const float4*)&z[(size_t)row0 * KDIM + kc + s * 4];
            *(float4*)&zr1[s * 4] =
                *(const float4*)&z[(size_t)(row0 + 1) * KDIM + kc + s * 4];
        }

#pragma unroll
        for (int kk = 0; kk < KC; ++kk) {
            float bv[28];
#pragma unroll
            for (int c = 0; c < 28; ++c) bv[c] = bt[kk][n0 + c];
            const float z0 = zr0[kk];
            const float z1 = zr1[kk];
#pragma unroll
            for (int c = 0; c < 28; ++c) {
                acc0[c] = fmaf(z0, bv[c], acc0[c]);
                acc1[c] = fmaf(z1, bv[c], acc1[c]);
            }
        }
    }

    // store lie_alg tile (cols >= 100 are padding, dropped)
#pragma unroll
    for (int c = 0; c < 28; ++c) {
        const int n = n0 + c;
        if (n < NDIM) {
            out[(size_t)row0 * NDIM + n]       = acc0[c];
            out[(size_t)(row0 + 1) * NDIM + n] = acc1[c];
        }
    }
}

// ---------------------------------------------------------------------------
// Kernel 2: out[b] = expm(out[b]) in place, one thread per 10x10 matrix.
// ||A|| ~ 0.15-0.25  =>  degree-10 Taylor via row-wise Horner:
//   u^T <- e_i^T + (u^T A) / k ,  k = N..1   gives row i of expm(A).
// Thread-private in-place rewrite: A fully loaded to registers before stores.
// ---------------------------------------------------------------------------
__global__ __launch_bounds__(256) void lie_expm_kernel(float* __restrict__ out)
{
    const int b = blockIdx.x * 256 + threadIdx.x;
    const size_t base = (size_t)b * NDIM;

    float A[100];
#pragma unroll
    for (int s = 0; s < 25; ++s)
        *(float4*)&A[s * 4] = *(const float4*)&out[base + s * 4];

#pragma unroll 1
    for (int i = 0; i < 10; ++i) {
        float u[10];
#pragma unroll
        for (int j = 0; j < 10; ++j) u[j] = (j == i) ? 1.f : 0.f;

#pragma unroll 1
        for (int k = NTERMS; k >= 1; --k) {
            float tmp[10];
#pragma unroll
            for (int j = 0; j < 10; ++j) tmp[j] = 0.f;
#pragma unroll
            for (int m = 0; m < 10; ++m) {
                const float um = u[m];
#pragma unroll
                for (int j = 0; j < 10; ++j)
                    tmp[j] = fmaf(um, A[m * 10 + j], tmp[j]);
            }
            const float inv = 1.f / (float)k;
#pragma unroll
            for (int j = 0; j < 10; ++j)
                u[j] = ((j == i) ? 1.f : 0.f) + tmp[j] * inv;
        }

        // row store: 10 floats, 8B-aligned -> 5x float2
#pragma unroll
        for (int s = 0; s < 5; ++s) {
            float2 v;
            v.x = u[s * 2];
            v.y = u[s * 2 + 1];
            *(float2*)&out[base + (size_t)i * 10 + s * 2] = v;
        }
    }
}

extern "C" void kernel_launch(void* const* d_in, const int* in_sizes, int n_in,
                              void* d_out, int out_size, void* d_ws, size_t ws_size,
                              hipStream_t stream)
{
    const float* z     = (const float*)d_in[0];
    const float* basis = (const float*)d_in[1];
    float* out         = (float*)d_out;

    lie_gemm_kernel<<<B_TOTAL / MT, 256, 0, stream>>>(z, basis, out);
    lie_expm_kernel<<<B_TOTAL / 256, 256, 0, stream>>>(out);
}

// Round 2
// 551.153 us; speedup vs baseline: 1.0922x; 1.0922x over previous
//
#include <hip/hip_runtime.h>

#define B_TOTAL 131072
#define KDIM    512
#define NDIM    100
#define NPAD    112      // 7 n-tiles of 16
#define MT      128      // batch rows per block
#define KC      64       // k per staged chunk (2 mfma k-steps)
#define NT      7        // n tiles per wave
#define ZSTR    (KC + 8) // LDS row stride (bf16 elems): 72 -> 144 B, 2-way-max banks
#define BSTR    (KC + 8)
#define NTERMS  7        // Taylor degree for expm (tail ~4e-10 at ||A||~0.15)

using bf16x8 = __attribute__((ext_vector_type(8))) short;
using f32x4  = __attribute__((ext_vector_type(4))) float;

// round-to-nearest-even fp32 -> bf16 (bit trick; NaN path irrelevant here)
__device__ __forceinline__ unsigned short f2bf(float x) {
    union { float f; unsigned u; } v; v.f = x;
    unsigned r = v.u + 0x7fffu + ((v.u >> 16) & 1u);
    return (unsigned short)(r >> 16);
}

// ---------------------------------------------------------------------------
// Kernel 1: lie_alg = z @ basis via bf16 MFMA (fp32 accumulate).
// fp32->bf16 conversion fused into LDS staging: HBM traffic = 268 MB z read
// + 52 MB lie_alg write (memory-bound floor ~55 us).
// Block: 256 thr = 4 waves; wave handles 32 rows (2 m-tiles) x 112 cols (7 n-tiles).
// LDS: zt[m][k] bf16 stride 72, bt[n][k] bf16 stride 72 (transposed basis so
// both A and B frags are 16B-contiguous ds_read_b128, worst 2-way conflicts).
// ---------------------------------------------------------------------------
__global__ __launch_bounds__(256, 3) void lie_gemm_mfma(
    const float* __restrict__ z, const float* __restrict__ basis,
    float* __restrict__ out)
{
    __shared__ unsigned short zt[MT * ZSTR];    // 18432 B
    __shared__ unsigned short bt[NPAD * BSTR];  // 16128 B

    const int t    = threadIdx.x;
    const int wave = t >> 6;
    const int lane = t & 63;
    const int b0   = blockIdx.x * MT;

    // zero the n-padding rows of bt once (never written again)
    for (int i = t; i < (NPAD - NDIM) * BSTR; i += 256)
        bt[NDIM * BSTR + i] = 0;

    f32x4 acc[2][NT];
#pragma unroll
    for (int mt = 0; mt < 2; ++mt)
#pragma unroll
        for (int nt = 0; nt < NT; ++nt)
            acc[mt][nt] = (f32x4){0.f, 0.f, 0.f, 0.f};

    const int kq = (lane >> 4) * 8;   // k sub-offset within a 32-wide mfma step
    const int ln = lane & 15;         // m (A) / n (B) index within tile
    const int m0 = wave * 32;

    for (int kc = 0; kc < KDIM; kc += KC) {
        __syncthreads();
        // stage z chunk: 128 rows x 64 k fp32 -> bf16. 2048 float4 loads.
#pragma unroll
        for (int it = 0; it < 8; ++it) {
            const int idx = t + it * 256;      // 0..2047
            const int row = idx >> 4;          // 16 float4 per row
            const int k4  = (idx & 15) * 4;
            const float4 v = *(const float4*)&z[(size_t)(b0 + row) * KDIM + kc + k4];
            ushort4 h;
            h.x = f2bf(v.x); h.y = f2bf(v.y); h.z = f2bf(v.z); h.w = f2bf(v.w);
            *(ushort4*)&zt[row * ZSTR + k4] = h;
        }
        // stage basis chunk transposed: [kc..kc+64) x 100 -> bt[n][k]
#pragma unroll
        for (int it = 0; it < 25; ++it) {
            const int idx = t + it * 256;      // 0..6399
            const int r = idx / 100;           // k within chunk
            const int c = idx - r * 100;       // n
            bt[c * BSTR + r] = f2bf(basis[(size_t)(kc + r) * NDIM + c]);
        }
        __syncthreads();

#pragma unroll
        for (int ks = 0; ks < KC; ks += 32) {
            const bf16x8 a0 = *(const bf16x8*)&zt[(m0 + ln) * ZSTR + ks + kq];
            const bf16x8 a1 = *(const bf16x8*)&zt[(m0 + 16 + ln) * ZSTR + ks + kq];
#pragma unroll
            for (int nt = 0; nt < NT; ++nt) {
                const bf16x8 bf = *(const bf16x8*)&bt[(nt * 16 + ln) * BSTR + ks + kq];
                acc[0][nt] = __builtin_amdgcn_mfma_f32_16x16x32_bf16(a0, bf, acc[0][nt], 0, 0, 0);
                acc[1][nt] = __builtin_amdgcn_mfma_f32_16x16x32_bf16(a1, bf, acc[1][nt], 0, 0, 0);
            }
        }
    }

    // epilogue: C/D layout col=lane&15, row=(lane>>4)*4+reg (m89/m91-verified)
#pragma unroll
    for (int mt = 0; mt < 2; ++mt) {
        const int mbase = b0 + wave * 32 + mt * 16 + ((lane >> 4) << 2);
#pragma unroll
        for (int nt = 0; nt < NT; ++nt) {
            const int n = nt * 16 + ln;
            if (n < NDIM) {
#pragma unroll
                for (int r = 0; r < 4; ++r)
                    out[(size_t)(mbase + r) * NDIM + n] = acc[mt][nt][r];
            }
        }
    }
}

// ---------------------------------------------------------------------------
// Kernel 2: out[b] = expm(out[b]) in place, one thread per 10x10 matrix.
// Degree-7 Taylor, row-wise Horner. launch_bounds(256,2) -> <=256 VGPR so
// A[100]+u+tmp (~150 regs) stays in registers (R1 theory: default cap spilled).
// ---------------------------------------------------------------------------
__global__ __launch_bounds__(256, 2) void lie_expm_kernel(float* __restrict__ out)
{
    const int b = blockIdx.x * 256 + threadIdx.x;
    const size_t base = (size_t)b * NDIM;

    float A[100];
#pragma unroll
    for (int s = 0; s < 25; ++s)
        *(float4*)&A[s * 4] = *(const float4*)&out[base + s * 4];

#pragma unroll 1
    for (int i = 0; i < 10; ++i) {
        float u[10];
#pragma unroll
        for (int j = 0; j < 10; ++j) u[j] = (j == i) ? 1.f : 0.f;

#pragma unroll 1
        for (int k = NTERMS; k >= 1; --k) {
            float tmp[10];
#pragma unroll
            for (int j = 0; j < 10; ++j) tmp[j] = 0.f;
#pragma unroll
            for (int m = 0; m < 10; ++m) {
                const float um = u[m];
#pragma unroll
                for (int j = 0; j < 10; ++j)
                    tmp[j] = fmaf(um, A[m * 10 + j], tmp[j]);
            }
            const float inv = 1.f / (float)k;
#pragma unroll
            for (int j = 0; j < 10; ++j)
                u[j] = ((j == i) ? 1.f : 0.f) + tmp[j] * inv;
        }

#pragma unroll
        for (int s = 0; s < 5; ++s) {
            float2 v;
            v.x = u[s * 2];
            v.y = u[s * 2 + 1];
            *(float2*)&out[base + (size_t)i * 10 + s * 2] = v;
        }
    }
}

extern "C" void kernel_launch(void* const* d_in, const int* in_sizes, int n_in,
                              void* d_out, int out_size, void* d_ws, size_t ws_size,
                              hipStream_t stream)
{
    const float* z     = (const float*)d_in[0];
    const float* basis = (const float*)d_in[1];
    float* out         = (float*)d_out;

    lie_gemm_mfma<<<B_TOTAL / MT, 256, 0, stream>>>(z, basis, out);
    lie_expm_kernel<<<B_TOTAL / 256, 256, 0, stream>>>(out);
}

// Round 3
// 425.605 us; speedup vs baseline: 1.4144x; 1.2950x over previous
//
#include <hip/hip_runtime.h>

#define B_TOTAL 131072
#define KDIM    512
#define NDIM    100
#define NPAD    112      // 7 n-tiles of 16
#define NT      7        // n tiles per wave
#define NTERMS  7        // Taylor degree for expm (tail ~2e-9 even at 3sigma ||A||)

using bf16x8 = __attribute__((ext_vector_type(8))) short;
using f32x4  = __attribute__((ext_vector_type(4))) float;

// round-to-nearest-even fp32 -> bf16 (bit trick; NaN path irrelevant here)
__device__ __forceinline__ unsigned short f2bf(float x) {
    union { float f; unsigned u; } v; v.f = x;
    unsigned r = v.u + 0x7fffu + ((v.u >> 16) & 1u);
    return (unsigned short)(r >> 16);
}

// ---------------------------------------------------------------------------
// Kernel 0 (prep): btT[n][k] = bf16(basis[k][n]), n padded to 112 with zeros.
// 115 KB into d_ws; runs once per launch, L2-resident for the GEMM.
// ---------------------------------------------------------------------------
__global__ __launch_bounds__(256) void basis_prep_kernel(
    const float* __restrict__ basis, unsigned short* __restrict__ btT)
{
    const int idx = blockIdx.x * 256 + threadIdx.x;   // 0 .. 112*512-1
    const int n = idx >> 9;          // 0..111
    const int k = idx & 511;
    btT[idx] = (n < NDIM) ? f2bf(basis[(size_t)k * NDIM + n]) : (unsigned short)0;
}

// ---------------------------------------------------------------------------
// Kernel 1: lie_alg = z @ basis via bf16 MFMA — NO LDS, NO BARRIERS.
// R2 post-mortem: barrier-locked staging serialized global loads (~1 load in
// flight per CU, 807 GB/s). Here every wave owns 32 rows x 112 cols and loads
// A-frags straight from z (fp32->bf16 pack in regs, each 64B line read once)
// and B-frags straight from btT (16B contiguous, L2-resident). Loads pipeline
// freely across k-steps; kernel should be z-bandwidth-bound.
// ---------------------------------------------------------------------------
__global__ __launch_bounds__(256) void lie_gemm_direct(
    const float* __restrict__ z, const unsigned short* __restrict__ btT,
    float* __restrict__ out)
{
    const int t    = threadIdx.x;
    const int wave = t >> 6;
    const int lane = t & 63;
    const int ln   = lane & 15;         // m (A) / n (B) index within 16-tile
    const int kq   = (lane >> 4) * 8;   // k sub-offset within 32-wide mfma step
    const int m0   = blockIdx.x * 128 + wave * 32;

    const float* zr0 = &z[(size_t)(m0 + ln) * KDIM + kq];
    const float* zr1 = zr0 + (size_t)16 * KDIM;
    const unsigned short* bp = &btT[(size_t)ln * KDIM + kq];

    f32x4 acc[2][NT];
#pragma unroll
    for (int mt = 0; mt < 2; ++mt)
#pragma unroll
        for (int nt = 0; nt < NT; ++nt)
            acc[mt][nt] = (f32x4){0.f, 0.f, 0.f, 0.f};

#pragma unroll 1
    for (int ks = 0; ks < KDIM; ks += 32) {
        const float4 va0 = *(const float4*)&zr0[ks];
        const float4 va1 = *(const float4*)&zr0[ks + 4];
        const float4 vb0 = *(const float4*)&zr1[ks];
        const float4 vb1 = *(const float4*)&zr1[ks + 4];

        bf16x8 a0, a1;
        a0[0] = f2bf(va0.x); a0[1] = f2bf(va0.y); a0[2] = f2bf(va0.z); a0[3] = f2bf(va0.w);
        a0[4] = f2bf(va1.x); a0[5] = f2bf(va1.y); a0[6] = f2bf(va1.z); a0[7] = f2bf(va1.w);
        a1[0] = f2bf(vb0.x); a1[1] = f2bf(vb0.y); a1[2] = f2bf(vb0.z); a1[3] = f2bf(vb0.w);
        a1[4] = f2bf(vb1.x); a1[5] = f2bf(vb1.y); a1[6] = f2bf(vb1.z); a1[7] = f2bf(vb1.w);

#pragma unroll
        for (int nt = 0; nt < NT; ++nt) {
            const bf16x8 bf = *(const bf16x8*)&bp[(size_t)nt * 16 * KDIM + ks];
            acc[0][nt] = __builtin_amdgcn_mfma_f32_16x16x32_bf16(a0, bf, acc[0][nt], 0, 0, 0);
            acc[1][nt] = __builtin_amdgcn_mfma_f32_16x16x32_bf16(a1, bf, acc[1][nt], 0, 0, 0);
        }
    }

    // epilogue: C/D layout col=lane&15, row=(lane>>4)*4+reg (m89/m91-verified)
#pragma unroll
    for (int mt = 0; mt < 2; ++mt) {
        const int mbase = m0 + mt * 16 + ((lane >> 4) << 2);
#pragma unroll
        for (int nt = 0; nt < NT; ++nt) {
            const int n = nt * 16 + ln;
            if (n < NDIM) {
#pragma unroll
                for (int r = 0; r < 4; ++r)
                    out[(size_t)(mbase + r) * NDIM + n] = acc[mt][nt][r];
            }
        }
    }
}

// ---------------------------------------------------------------------------
// Kernel 2: out[b] = expm(out[b]) in place, one thread per 10x10 matrix.
// Degree-7 Taylor, row-wise Horner. R2 post-mortem: type-punning float4 casts
// on the LOCAL array defeated mem2reg -> A[100] lived in scratch (~3.7 GB of
// buffer-load traffic). All local-array access is now element-wise with
// constant indices so A/u/tmp stay in VGPRs.
// ---------------------------------------------------------------------------
__global__ __launch_bounds__(256, 2) void lie_expm_kernel(float* __restrict__ out)
{
    const int b = blockIdx.x * 256 + threadIdx.x;
    const size_t base = (size_t)b * NDIM;

    float A[100];
#pragma unroll
    for (int s = 0; s < 25; ++s) {
        const float4 v = *(const float4*)&out[base + s * 4];  // global: cast OK
        A[s * 4 + 0] = v.x;
        A[s * 4 + 1] = v.y;
        A[s * 4 + 2] = v.z;
        A[s * 4 + 3] = v.w;
    }

#pragma unroll 1
    for (int i = 0; i < 10; ++i) {
        float u[10];
#pragma unroll
        for (int j = 0; j < 10; ++j) u[j] = (j == i) ? 1.f : 0.f;

#pragma unroll 1
        for (int k = NTERMS; k >= 1; --k) {
            float tmp[10];
#pragma unroll
            for (int j = 0; j < 10; ++j) tmp[j] = 0.f;
#pragma unroll
            for (int m = 0; m < 10; ++m) {
                const float um = u[m];
#pragma unroll
                for (int j = 0; j < 10; ++j)
                    tmp[j] = fmaf(um, A[m * 10 + j], tmp[j]);
            }
            const float inv = 1.f / (float)k;
#pragma unroll
            for (int j = 0; j < 10; ++j)
                u[j] = ((j == i) ? 1.f : 0.f) + tmp[j] * inv;
        }

#pragma unroll
        for (int s = 0; s < 5; ++s) {
            float2 v;
            v.x = u[s * 2];
            v.y = u[s * 2 + 1];
            *(float2*)&out[base + (size_t)i * 10 + s * 2] = v;  // global: cast OK
        }
    }
}

extern "C" void kernel_launch(void* const* d_in, const int* in_sizes, int n_in,
                              void* d_out, int out_size, void* d_ws, size_t ws_size,
                              hipStream_t stream)
{
    const float* z     = (const float*)d_in[0];
    const float* basis = (const float*)d_in[1];
    float* out         = (float*)d_out;
    unsigned short* btT = (unsigned short*)d_ws;   // 112*512*2 = 114688 B

    basis_prep_kernel<<<(NPAD * KDIM) / 256, 256, 0, stream>>>(basis, btT);
    lie_gemm_direct<<<B_TOTAL / 128, 256, 0, stream>>>(z, btT, out);
    lie_expm_kernel<<<B_TOTAL / 256, 256, 0, stream>>>(out);
}